// Round 1
// baseline (57.899 us; speedup 1.0000x reference)
//
#include <hip/hip_runtime.h>
#include <math.h>

// Problem constants (from reference setup_inputs)
#define B_ 32
#define S_ 8192
#define H_ 256
#define CHUNK_ 512                      // rows per block
#define WAVES_PB 4                      // 256 threads
#define WROWS (CHUNK_ / WAVES_PB)       // 128 rows per wave
#define TILE_ 16                        // rows per register tile
#define NCHUNK (S_ / CHUNK_)            // 16 blocks per batch
#define NPART (B_ * NCHUNK * WAVES_PB)  // 2048 per-wave partials
#define PPB (NCHUNK * WAVES_PB)         // 64 partials per batch

// K1: flash-style single pass over encoder_states.
// Each wave: 128 rows of one batch, tiles of 16 rows held in registers.
// Emits raw scores (into d_out prob region, fixed up in-place by K3) and
// per-wave partial (m, l, c[256]).
__global__ __launch_bounds__(256) void
k1_flash(const float* __restrict__ dec, const float* __restrict__ enc,
         float* __restrict__ scores_out, float* __restrict__ pm,
         float* __restrict__ pl, float* __restrict__ pc) {
    const int lane  = threadIdx.x & 63;
    const int wave  = threadIdx.x >> 6;
    const int batch = blockIdx.x >> 4;       // / NCHUNK
    const int chunk = blockIdx.x & (NCHUNK - 1);
    const int rowBase = chunk * CHUNK_ + wave * WROWS;

    const float4 d = *(const float4*)(dec + batch * H_ + lane * 4);
    const float* ebase = enc + (size_t)batch * S_ * H_;

    float  m = -INFINITY, l = 0.f;
    float4 c = make_float4(0.f, 0.f, 0.f, 0.f);

    for (int t = 0; t < WROWS / TILE_; ++t) {
        const int r0 = rowBase + t * TILE_;
        float4 v[TILE_];
        float  sc[TILE_];
#pragma unroll
        for (int r = 0; r < TILE_; ++r) {
            v[r] = *(const float4*)(ebase + (size_t)(r0 + r) * H_ + lane * 4);
            float sp = v[r].x * d.x + v[r].y * d.y + v[r].z * d.z + v[r].w * d.w;
#pragma unroll
            for (int off = 32; off; off >>= 1) sp += __shfl_xor(sp, off);
            sc[r] = sp;                      // all 64 lanes hold the row sum
        }
        float tmax = sc[0];
#pragma unroll
        for (int r = 1; r < TILE_; ++r) tmax = fmaxf(tmax, sc[r]);
        const float mnew = fmaxf(m, tmax);
        const float f = __expf(m - mnew);    // first tile: exp(-inf)=0
        c.x *= f; c.y *= f; c.z *= f; c.w *= f;
        l *= f;
        m = mnew;
#pragma unroll
        for (int r = 0; r < TILE_; ++r) {
            const float p = __expf(sc[r] - m);
            l += p;
            c.x += p * v[r].x;
            c.y += p * v[r].y;
            c.z += p * v[r].z;
            c.w += p * v[r].w;
        }
        if (lane == 0) {                     // raw scores, 4x float4
            float* so = scores_out + batch * S_ + r0;
            *(float4*)(so + 0)  = make_float4(sc[0],  sc[1],  sc[2],  sc[3]);
            *(float4*)(so + 4)  = make_float4(sc[4],  sc[5],  sc[6],  sc[7]);
            *(float4*)(so + 8)  = make_float4(sc[8],  sc[9],  sc[10], sc[11]);
            *(float4*)(so + 12) = make_float4(sc[12], sc[13], sc[14], sc[15]);
        }
    }

    const int pid = blockIdx.x * WAVES_PB + wave;
    *(float4*)(pc + (size_t)pid * H_ + lane * 4) = c;
    if (lane == 0) { pm[pid] = m; pl[pid] = l; }
}

// K2: combine 64 per-wave partials per batch -> context; write final M, 1/L.
__global__ __launch_bounds__(256) void
k2_combine(const float* __restrict__ pm, const float* __restrict__ pl,
           const float* __restrict__ pc, float* __restrict__ ctx_out,
           float* __restrict__ fm, float* __restrict__ frl) {
    const int b = blockIdx.x;
    const int h = threadIdx.x;
    float M = -INFINITY;
    for (int i = 0; i < PPB; ++i) M = fmaxf(M, pm[b * PPB + i]);
    float L = 0.f, acc = 0.f;
    for (int i = 0; i < PPB; ++i) {
        const float w = __expf(pm[b * PPB + i] - M);
        L   += w * pl[b * PPB + i];
        acc += w * pc[(size_t)(b * PPB + i) * H_ + h];
    }
    ctx_out[b * H_ + h] = acc / L;
    if (h == 0) { fm[b] = M; frl[b] = 1.f / L; }
}

// K3: in-place score -> prob, float4 per thread.
__global__ __launch_bounds__(256) void
k3_prob(float* __restrict__ probs, const float* __restrict__ fm,
        const float* __restrict__ frl) {
    const int i = blockIdx.x * blockDim.x + threadIdx.x;  // float4 index
    const int b = i / (S_ / 4);
    float4 v = ((const float4*)probs)[i];
    const float M = fm[b], R = frl[b];
    v.x = __expf(v.x - M) * R;
    v.y = __expf(v.y - M) * R;
    v.z = __expf(v.z - M) * R;
    v.w = __expf(v.w - M) * R;
    ((float4*)probs)[i] = v;
}

extern "C" void kernel_launch(void* const* d_in, const int* in_sizes, int n_in,
                              void* d_out, int out_size, void* d_ws, size_t ws_size,
                              hipStream_t stream) {
    const float* dec = (const float*)d_in[0];
    const float* enc = (const float*)d_in[1];
    float* out    = (float*)d_out;
    float* scores = out;              // [B_*S_] prob region doubles as scratch
    float* ctx    = out + B_ * S_;    // [B_*H_]

    float* pm  = (float*)d_ws;                 // [NPART]
    float* pl  = pm + NPART;                   // [NPART]
    float* pc  = pl + NPART;                   // [NPART*H_]
    float* fm  = pc + (size_t)NPART * H_;      // [B_]
    float* frl = fm + B_;                      // [B_]

    k1_flash<<<B_ * NCHUNK, 256, 0, stream>>>(dec, enc, scores, pm, pl, pc);
    k2_combine<<<B_, 256, 0, stream>>>(pm, pl, pc, ctx, fm, frl);
    k3_prob<<<(B_ * S_ / 4) / 256, 256, 0, stream>>>(scores, fm, frl);
}

// Round 2
// 52.152 us; speedup vs baseline: 1.1102x; 1.1102x over previous
//
#include <hip/hip_runtime.h>
#include <math.h>

// Problem constants (from reference setup_inputs)
#define B_ 32
#define S_ 8192
#define H_ 256
#define CHUNK_ 512                      // rows per block
#define WAVES_PB 4                      // 256 threads
#define WROWS (CHUNK_ / WAVES_PB)       // 128 rows per wave
#define TILE_ 16                        // rows per register tile
#define NCHUNK (S_ / CHUNK_)            // 16 blocks per batch
#define NPART (B_ * NCHUNK * WAVES_PB)  // 2048 per-wave partials
#define PPB (NCHUNK * WAVES_PB)         // 64 partials per batch (== wave width!)

// K1: flash-style single pass over encoder_states.
// Each wave: 128 rows of one batch, tiles of 16 rows held in registers.
// Emits raw scores (into d_out prob region, fixed up in-place by K23) and
// per-wave partial (m, l, c[256]).
__global__ __launch_bounds__(256) void
k1_flash(const float* __restrict__ dec, const float* __restrict__ enc,
         float* __restrict__ scores_out, float* __restrict__ pm,
         float* __restrict__ pl, float* __restrict__ pc) {
    const int lane  = threadIdx.x & 63;
    const int wave  = threadIdx.x >> 6;
    const int batch = blockIdx.x >> 4;       // / NCHUNK
    const int chunk = blockIdx.x & (NCHUNK - 1);
    const int rowBase = chunk * CHUNK_ + wave * WROWS;

    const float4 d = *(const float4*)(dec + batch * H_ + lane * 4);
    const float* ebase = enc + (size_t)batch * S_ * H_;

    float  m = -INFINITY, l = 0.f;
    float4 c = make_float4(0.f, 0.f, 0.f, 0.f);

    for (int t = 0; t < WROWS / TILE_; ++t) {
        const int r0 = rowBase + t * TILE_;
        float4 v[TILE_];
        float  sc[TILE_];
#pragma unroll
        for (int r = 0; r < TILE_; ++r) {
            v[r] = *(const float4*)(ebase + (size_t)(r0 + r) * H_ + lane * 4);
            float sp = v[r].x * d.x + v[r].y * d.y + v[r].z * d.z + v[r].w * d.w;
#pragma unroll
            for (int off = 32; off; off >>= 1) sp += __shfl_xor(sp, off);
            sc[r] = sp;                      // all 64 lanes hold the row sum
        }
        float tmax = sc[0];
#pragma unroll
        for (int r = 1; r < TILE_; ++r) tmax = fmaxf(tmax, sc[r]);
        const float mnew = fmaxf(m, tmax);
        const float f = __expf(m - mnew);    // first tile: exp(-inf)=0
        c.x *= f; c.y *= f; c.z *= f; c.w *= f;
        l *= f;
        m = mnew;
#pragma unroll
        for (int r = 0; r < TILE_; ++r) {
            const float p = __expf(sc[r] - m);
            l += p;
            c.x += p * v[r].x;
            c.y += p * v[r].y;
            c.z += p * v[r].z;
            c.w += p * v[r].w;
        }
        if (lane == 0) {                     // raw scores, 4x float4
            float* so = scores_out + batch * S_ + r0;
            *(float4*)(so + 0)  = make_float4(sc[0],  sc[1],  sc[2],  sc[3]);
            *(float4*)(so + 4)  = make_float4(sc[4],  sc[5],  sc[6],  sc[7]);
            *(float4*)(so + 8)  = make_float4(sc[8],  sc[9],  sc[10], sc[11]);
            *(float4*)(so + 12) = make_float4(sc[12], sc[13], sc[14], sc[15]);
        }
    }

    const int pid = blockIdx.x * WAVES_PB + wave;
    *(float4*)(pc + (size_t)pid * H_ + lane * 4) = c;
    if (lane == 0) { pm[pid] = m; pl[pid] = l; }
}

// K23: fused finish. Blocks 0..255: prob fixup (in-place exp(sc-M)/L).
// Blocks 256..287: context combine. Both derive (M, L) directly from the
// 64 per-batch partials via a 64-lane butterfly (PPB == 64 == wave width).
__global__ __launch_bounds__(256) void
k23_finish(const float* __restrict__ pm, const float* __restrict__ pl,
           const float* __restrict__ pc, float* __restrict__ probs,
           float* __restrict__ ctx_out) {
    const int lane = threadIdx.x & 63;

    if (blockIdx.x < 256) {
        // ---- prob fixup: 8 blocks per batch, 1024 floats per block ----
        const int b = blockIdx.x >> 3;
        const float pmv = pm[b * PPB + lane];
        const float plv = pl[b * PPB + lane];
        float M = pmv;
#pragma unroll
        for (int off = 32; off; off >>= 1) M = fmaxf(M, __shfl_xor(M, off));
        float Lp = __expf(pmv - M) * plv;
#pragma unroll
        for (int off = 32; off; off >>= 1) Lp += __shfl_xor(Lp, off);
        const float R = 1.f / Lp;

        float* p = probs + b * S_ + (blockIdx.x & 7) * 1024 + threadIdx.x * 4;
        float4 v = *(const float4*)p;
        v.x = __expf(v.x - M) * R;
        v.y = __expf(v.y - M) * R;
        v.z = __expf(v.z - M) * R;
        v.w = __expf(v.w - M) * R;
        *(float4*)p = v;
    } else {
        // ---- context combine: one block per batch ----
        const int b = blockIdx.x - 256;
        const int h = threadIdx.x;
        const float pmv = pm[b * PPB + lane];
        const float plv = pl[b * PPB + lane];
        float M = pmv;
#pragma unroll
        for (int off = 32; off; off >>= 1) M = fmaxf(M, __shfl_xor(M, off));
        const float w = __expf(pmv - M);     // per-lane rescale weight
        float L = w * plv;
#pragma unroll
        for (int off = 32; off; off >>= 1) L += __shfl_xor(L, off);

        float acc = 0.f;
        const float* pcb = pc + (size_t)b * PPB * H_ + h;
#pragma unroll 8
        for (int i = 0; i < PPB; ++i) {
            acc += __shfl(w, i) * pcb[(size_t)i * H_];
        }
        ctx_out[b * H_ + h] = acc / L;
    }
}

extern "C" void kernel_launch(void* const* d_in, const int* in_sizes, int n_in,
                              void* d_out, int out_size, void* d_ws, size_t ws_size,
                              hipStream_t stream) {
    const float* dec = (const float*)d_in[0];
    const float* enc = (const float*)d_in[1];
    float* out    = (float*)d_out;
    float* scores = out;              // [B_*S_] prob region doubles as scratch
    float* ctx    = out + B_ * S_;    // [B_*H_]

    float* pm = (float*)d_ws;                  // [NPART]
    float* pl = pm + NPART;                    // [NPART]
    float* pc = pl + NPART;                    // [NPART*H_]

    k1_flash<<<B_ * NCHUNK, 256, 0, stream>>>(dec, enc, scores, pm, pl, pc);
    k23_finish<<<256 + B_, 256, 0, stream>>>(pm, pl, pc, scores, ctx);
}